// Round 12
// baseline (1125.355 us; speedup 1.0000x reference)
//
#include <hip/hip_runtime.h>
#include <hip/hip_fp16.h>
#include <math.h>

// Reference: bev (1024,1,120,120) fp32 -> out (1024,120) fp32.
// R10 green @955us (VALU-bound). R11 failed on a typo: thi used fminf(ay0,ay1)
// (y-ENTRY) instead of fmaxf -> truncated t-windows -> garbage sinogram.
// R12 = R11 with: (a) the typo fixed; (b) window tightened to [0,121) — exact
// (px or py in [121,122) touches only zero pads) AND makes +eps drift
// in-bounds (fy<=121 max row); (c) fmaxf(,0) on BOTH coords so -eps drift
// can't index H[-1] (px=-eps at fy=0 was OOB in R11's scheme).
#define NPIX  120
#define NS    120
#define NK    61
#define HSTR  123            // H columns: x 0..122 (pad cols 0, 121, 122)
#define HROWS 122            // H rows: y 0..121; H[y] = (P[y], P[y+1])
#define CHUNK 8
#define NCHUNK 15
#define NT    960

typedef float vf2 __attribute__((ext_vector_type(2)));

// LDS: 122*123*4 (60,024) + 8*120*4 (3,840) + 61*4 + 4 = 64,112 B.

__global__ void ring_fused(const float* __restrict__ bev,
                           float* __restrict__ out,
                           int B) {
    __shared__ __half2 H[HROWS * HSTR];   // y-pair packed zero-padded image
    __shared__ float schunk[CHUNK * NS];
    __shared__ float outAcc[NK];
    __shared__ float invNorm;

    const int tid = threadIdx.x;          // 0..959
    const int b   = blockIdx.x;
    const int al  = tid / NS;             // angle slot 0..7
    const int sk  = tid - al * NS;        // s (radon) / k (Goertzel, <61)
    if (b >= B) return;

    // ---- stage: build half2 y-pair image ----------------------------------
    // H[y][x].lo = P[y][x] = img[y-1][x-1] (0 if OOB); .hi = P[y+1][x]
    const float* src = bev + (size_t)b * (NPIX * NPIX);
    for (int i = tid; i < HROWS * HSTR; i += NT) {
        int y = i / HSTR, x = i - y * HSTR;
        float lo = 0.f, hi = 0.f;
        int gx = x - 1;
        if (gx >= 0 && gx < NPIX) {
            int gyl = y - 1;
            if (gyl >= 0 && gyl < NPIX) lo = src[gyl * NPIX + gx];
            if (y < NPIX)               hi = src[y   * NPIX + gx];
        }
        H[i] = __floats2half2_rn(lo, hi);
    }
    __syncthreads();

    const float coef = 2.f * cosf((float)sk * 0.052359877559829887f);  // 2cos(pi k/60)
    const float sgn  = (sk & 1) ? -1.f : 1.f;
    const double STEP = 6.283185307179586 / 119.0;
    float accK = 0.f;

    for (int ch = 0; ch < NCHUNK; ++ch) {
        // ---- radon: sinogram[a = ch*8+al][s = sk] --------------------------
        {
            int a = ch * CHUNK + al;
            float theta = (float)((double)a * STEP);
            float st = sinf(theta), ct = cosf(theta);
            float sf = (float)sk - 59.5f;
            float Ax = fmaf(sf, ct, 60.5f);   // padded px at tv=0, in [1,120]
            float Ay = fmaf(sf, st, 60.5f);   // padded py at tv=0, in [1,120]
            float dx = -st, dy = ct;

            // t-window: tv where px,py in [0,121). Samples outside touch only
            // zero pads (exact). Ax,Ay >= 1 so no 0*inf NaN when a slope is 0.
            float ivx = 1.f / dx, ivy = 1.f / dy;
            float ax0 = (0.f - Ax) * ivx, ax1 = (121.f - Ax) * ivx;
            float ay0 = (0.f - Ay) * ivy, ay1 = (121.f - Ay) * ivy;
            float tlo = fmaxf(fminf(ax0, ax1), fminf(ay0, ay1));
            float thi = fminf(fmaxf(ax0, ax1), fmaxf(ay0, ay1));   // (typo fixed)
            int t0 = (int)fmaxf(ceilf(tlo + 59.5f), 0.f);
            int t1 = (int)fminf(floorf(thi + 59.5f), 119.f);

            float tv0 = (float)t0 - 59.5f;
            vf2 pos = { fmaf(tv0, dx, Ax), fmaf(tv0, dy, Ay) };
            vf2 d   = { dx, dy };
            float accT = 0.f, accD = 0.f;
            for (int t = t0; t <= t1; ++t) {
                float px = fmaxf(pos.x, 0.f);            // -eps drift guard
                float py = fmaxf(pos.y, 0.f);            // (OOB-safe: see header)
                float fx = floorf(px), fy = floorf(py);
                vf2 fl = { fx, fy };
                vf2 w  = { px, py };
                w -= fl;                                  // (wx, wy) packed sub
                int ai = (int)fmaf(fy, (float)HSTR, fx);  // exact (<2^24)
                __half2 h0 = H[ai];                       // (v00, v10)
                __half2 h1 = H[ai + 1];                   // (v01, v11) ds_read2_b32
                __half2 dv = __hsub2(h1, h0);
                __half2 tb = __hfma2(__float2half2_rn(w.x), dv, h0);  // (top,bot)
                float top = __low2float(tb);
                float bot = __high2float(tb);
                accT += top;
                accD = fmaf(w.y, bot - top, accD);
                pos += d;                                 // v_pk_add_f32
            }
            schunk[al * NS + sk] = accT + accD;
        }
        __syncthreads();

        // ---- Goertzel: |F[k = sk]| of row al (sk < 61), on-the-fly fold ----
        if (sk < NK) {
            const float* row = schunk + al * NS;
            float u1 = 0.f, u2 = 0.f;
            #pragma unroll 4
            for (int s = 0; s < 60; ++s) {
                float w = fmaf(sgn, row[s + 60], row[s]);  // broadcast reads
                float v = fmaf(coef, u1, w - u2);
                u2 = u1; u1 = v;
            }
            float power = fmaf(u1, u1, fmaf(u2, u2, -coef * u1 * u2));
            power = fmaxf(power, 0.f);
            accK += sqrtf(fmaf(power, (1.f / 120.f), 1e-15f));  // ortho + EPS_FFT
        }
        __syncthreads();
    }

    // ---- reduce 8 angle-slot partials per bin ------------------------------
    if (sk < NK) schunk[al * NS + sk] = accK;
    __syncthreads();
    if (tid < NK) {
        float s = 0.f;
        for (int a2 = 0; a2 < CHUNK; ++a2) s += schunk[a2 * NS + tid];
        outAcc[tid] = s;
    }
    __syncthreads();

    // ---- L2 norm over mirrored 120-vector ----------------------------------
    if (tid == 0) {
        float ssq = 0.f;
        for (int k = 0; k < NK; ++k) {
            float v = outAcc[k];
            float wgt = (k == 0 || k == 60) ? 1.f : 2.f;
            ssq = fmaf(wgt * v, v, ssq);
        }
        invNorm = 1.f / fmaxf(sqrtf(ssq), 1e-12f);
    }
    __syncthreads();

    // ---- write fp32 output (Hermitian mirror) ------------------------------
    if (tid < NPIX) {
        int k = (tid <= 60) ? tid : (NPIX - tid);
        out[(size_t)b * NPIX + tid] = outAcc[k] * invNorm;
    }
}

extern "C" void kernel_launch(void* const* d_in, const int* in_sizes, int n_in,
                              void* d_out, int out_size, void* d_ws, size_t ws_size,
                              hipStream_t stream) {
    const float* bev = (const float*)d_in[0];
    float* out = (float*)d_out;
    int B = in_sizes[0] / (NPIX * NPIX);   // 1024
    hipLaunchKernelGGL(ring_fused, dim3(B), dim3(NT), 0, stream, bev, out, B);
}

// Round 13
// 1050.164 us; speedup vs baseline: 1.0716x; 1.0716x over previous
//
#include <hip/hip_runtime.h>
#include <hip/hip_fp16.h>
#include <math.h>

// Reference: bev (1024,1,120,120) fp32 -> out (1024,120) fp32.
// R10 green @955us (VALU-bound). R12 green @1125us — per-lane variable trip
// count caused wave divergence + lost unrolling (lesson: skip must be
// wave-uniform). R13 = R10 chassis + (1) WAVE-UNIFORM t-window: per-lane
// exact window (R12-proven) -> wave union via shfl_xor min/max; med3 clamps
// kept so out-of-own-window lanes contribute exact zeros (R10-proven case
// analysis); trip rounded to even, manual 2x unroll, dual pos chains.
// (2) incremental packed coords (R12-proven @4.9e-4). (3) packed accumulate
// acc2 += (1-wy, wy)*(top,bot) via v_pk_fma_f32.
#define NPIX  120
#define NS    120
#define NK    61
#define HSTR  123            // H columns: x 0..122 (pad cols 0, 121, 122)
#define HROWS 122            // H rows: y 0..121; H[y] = (P[y], P[y+1])
#define CHUNK 8
#define NCHUNK 15
#define NT    960

typedef float vf2 __attribute__((ext_vector_type(2)));

// LDS: 122*123*4 (60,024) + 8*120*4 (3,840) + 61*4 + 4 = 64,112 B.

__global__ void ring_fused(const float* __restrict__ bev,
                           float* __restrict__ out,
                           int B) {
    __shared__ __half2 H[HROWS * HSTR];   // y-pair packed zero-padded image
    __shared__ float schunk[CHUNK * NS];
    __shared__ float outAcc[NK];
    __shared__ float invNorm;

    const int tid = threadIdx.x;          // 0..959
    const int b   = blockIdx.x;
    const int al  = tid / NS;             // angle slot 0..7
    const int sk  = tid - al * NS;        // s (radon) / k (Goertzel, <61)
    if (b >= B) return;

    // ---- stage: build half2 y-pair image ----------------------------------
    // H[y][x].lo = P[y][x] = img[y-1][x-1] (0 if OOB); .hi = P[y+1][x]
    const float* src = bev + (size_t)b * (NPIX * NPIX);
    for (int i = tid; i < HROWS * HSTR; i += NT) {
        int y = i / HSTR, x = i - y * HSTR;
        float lo = 0.f, hi = 0.f;
        int gx = x - 1;
        if (gx >= 0 && gx < NPIX) {
            int gyl = y - 1;
            if (gyl >= 0 && gyl < NPIX) lo = src[gyl * NPIX + gx];
            if (y < NPIX)               hi = src[y   * NPIX + gx];
        }
        H[i] = __floats2half2_rn(lo, hi);
    }
    __syncthreads();

    const float coef = 2.f * cosf((float)sk * 0.052359877559829887f);  // 2cos(pi k/60)
    const float sgn  = (sk & 1) ? -1.f : 1.f;
    const double STEP = 6.283185307179586 / 119.0;
    float accK = 0.f;

    for (int ch = 0; ch < NCHUNK; ++ch) {
        // ---- radon: sinogram[a = ch*8+al][s = sk] --------------------------
        {
            int a = ch * CHUNK + al;
            float theta = (float)((double)a * STEP);
            float st = sinf(theta), ct = cosf(theta);
            float sf = (float)sk - 59.5f;
            float Ax = fmaf(sf, ct, 60.5f);   // padded px at tv=0, in [1,120]
            float Ay = fmaf(sf, st, 60.5f);   // padded py at tv=0, in [1,120]
            float dx = -st, dy = ct;

            // per-lane exact window (R12-proven): tv where px,py in [0,121)
            float ivx = 1.f / dx, ivy = 1.f / dy;   // inf ok; Ax,Ay>=1 no 0*inf
            float ax0 = (0.f - Ax) * ivx, ax1 = (121.f - Ax) * ivx;
            float ay0 = (0.f - Ay) * ivy, ay1 = (121.f - Ay) * ivy;
            float tlo = fmaxf(fminf(ax0, ax1), fminf(ay0, ay1));
            float thi = fminf(fmaxf(ax0, ax1), fmaxf(ay0, ay1));
            int t0 = (int)fmaxf(ceilf(tlo + 59.5f), 0.f);
            int t1 = (int)fminf(floorf(thi + 59.5f), 119.f);

            // wave union -> uniform trip count (no divergence, clamps cover
            // lanes outside their own window with exact-zero contributions)
            #pragma unroll
            for (int off = 1; off < 64; off <<= 1) {
                t0 = min(t0, __shfl_xor(t0, off, 64));
                t1 = max(t1, __shfl_xor(t1, off, 64));
            }
            int cnt = (t1 - t0 + 2) & ~1;     // even (extra tail iter is
                                              // beyond every lane's window
                                              // -> clamped to exact zero)
            float tv0 = (float)t0 - 59.5f;
            vf2 posA = { fmaf(tv0, dx, Ax), fmaf(tv0, dy, Ay) };
            vf2 posB = { posA.x + dx, posA.y + dy };
            vf2 d2   = { dx + dx, dy + dy };
            vf2 acc2 = { 0.f, 0.f };          // (sum (1-wy)top, sum wy*bot)

            for (int i = 0; i < cnt; i += 2) {
                // sample A
                {
                    float cx = fminf(fmaxf(posA.x, 0.f), 121.f);  // med3
                    float cy = fminf(fmaxf(posA.y, 0.f), 121.f);
                    float fx = floorf(cx), fy = floorf(cy);
                    float wx = cx - fx,    wy = cy - fy;
                    int ai = (int)fmaf(fy, (float)HSTR, fx);
                    __half2 h0 = H[ai];                       // (v00, v10)
                    __half2 h1 = H[ai + 1];                   // ds_read2_b32
                    __half2 dv = __hsub2(h1, h0);
                    __half2 tb = __hfma2(__float2half2_rn(wx), dv, h0);
                    vf2 w2  = { 1.f - wy, wy };
                    vf2 tb2 = { __low2float(tb), __high2float(tb) };
                    acc2 += w2 * tb2;                         // v_pk_fma_f32
                    posA += d2;                               // v_pk_add_f32
                }
                // sample B
                {
                    float cx = fminf(fmaxf(posB.x, 0.f), 121.f);
                    float cy = fminf(fmaxf(posB.y, 0.f), 121.f);
                    float fx = floorf(cx), fy = floorf(cy);
                    float wx = cx - fx,    wy = cy - fy;
                    int ai = (int)fmaf(fy, (float)HSTR, fx);
                    __half2 h0 = H[ai];
                    __half2 h1 = H[ai + 1];
                    __half2 dv = __hsub2(h1, h0);
                    __half2 tb = __hfma2(__float2half2_rn(wx), dv, h0);
                    vf2 w2  = { 1.f - wy, wy };
                    vf2 tb2 = { __low2float(tb), __high2float(tb) };
                    acc2 += w2 * tb2;
                    posB += d2;
                }
            }
            schunk[al * NS + sk] = acc2.x + acc2.y;
        }
        __syncthreads();

        // ---- Goertzel: |F[k = sk]| of row al (sk < 61), on-the-fly fold ----
        if (sk < NK) {
            const float* row = schunk + al * NS;
            float u1 = 0.f, u2 = 0.f;
            #pragma unroll 4
            for (int s = 0; s < 60; ++s) {
                float w = fmaf(sgn, row[s + 60], row[s]);  // broadcast reads
                float v = fmaf(coef, u1, w - u2);
                u2 = u1; u1 = v;
            }
            float power = fmaf(u1, u1, fmaf(u2, u2, -coef * u1 * u2));
            power = fmaxf(power, 0.f);
            accK += sqrtf(fmaf(power, (1.f / 120.f), 1e-15f));  // ortho + EPS_FFT
        }
        __syncthreads();
    }

    // ---- reduce 8 angle-slot partials per bin ------------------------------
    if (sk < NK) schunk[al * NS + sk] = accK;
    __syncthreads();
    if (tid < NK) {
        float s = 0.f;
        for (int a2 = 0; a2 < CHUNK; ++a2) s += schunk[a2 * NS + tid];
        outAcc[tid] = s;
    }
    __syncthreads();

    // ---- L2 norm over mirrored 120-vector ----------------------------------
    if (tid == 0) {
        float ssq = 0.f;
        for (int k = 0; k < NK; ++k) {
            float v = outAcc[k];
            float wgt = (k == 0 || k == 60) ? 1.f : 2.f;
            ssq = fmaf(wgt * v, v, ssq);
        }
        invNorm = 1.f / fmaxf(sqrtf(ssq), 1e-12f);
    }
    __syncthreads();

    // ---- write fp32 output (Hermitian mirror) ------------------------------
    if (tid < NPIX) {
        int k = (tid <= 60) ? tid : (NPIX - tid);
        out[(size_t)b * NPIX + tid] = outAcc[k] * invNorm;
    }
}

extern "C" void kernel_launch(void* const* d_in, const int* in_sizes, int n_in,
                              void* d_out, int out_size, void* d_ws, size_t ws_size,
                              hipStream_t stream) {
    const float* bev = (const float*)d_in[0];
    float* out = (float*)d_out;
    int B = in_sizes[0] / (NPIX * NPIX);   // 1024
    hipLaunchKernelGGL(ring_fused, dim3(B), dim3(NT), 0, stream, bev, out, B);
}